// Round 6
// baseline (412.648 us; speedup 1.0000x reference)
//
#include <hip/hip_runtime.h>
#include <cmath>

#define D_ 4096
#define H_ 32
#define HD_ 128
#define B_ 8
#define MAXSEQ_ 2048
#define AL_ 10
#define FF_ 11008
#define NC_ 128                       // attention position-chunks (16 positions each)
#define SCALE_ 0.08838834764831845f   // 1/sqrt(128)
#define EPS_ 1e-5f

// ---------- fused: rmsnorm(x) -> xa rows 0..7 ; adapter copy -> xa rows 8..17 ----------
__global__ __launch_bounds__(256) void norm_adapter_k(const float* __restrict__ x,
                                                      const float* __restrict__ w,
                                                      const float* __restrict__ adapter,
                                                      float* __restrict__ xa) {
  int b = blockIdx.x, tid = threadIdx.x;
  if (b < 8) {
    const float* xr = x + (size_t)b * D_;
    float ss = 0.f;
    for (int i = tid; i < D_; i += 256) { float v = xr[i]; ss += v * v; }
    __shared__ float red[256];
    red[tid] = ss; __syncthreads();
    for (int s = 128; s; s >>= 1) { if (tid < s) red[tid] += red[tid + s]; __syncthreads(); }
    float r = rsqrtf(red[0] / (float)D_ + EPS_);
    float* o = xa + (size_t)b * D_;
    for (int i = tid; i < D_; i += 256) o[i] = xr[i] * r * w[i];
  } else {
    int r = b - 8;
    const float4* src = (const float4*)(adapter + (size_t)r * D_);
    float4* dst = (float4*)(xa + (size_t)(8 + r) * D_);
    for (int i = tid; i < D_ / 4; i += 256) dst[i] = src[i];
  }
}

__global__ __launch_bounds__(256) void rmsnorm_k(const float* __restrict__ in,
                                                 const float* __restrict__ w,
                                                 float* __restrict__ out) {
  int b = blockIdx.x, tid = threadIdx.x;
  const float* x = in + (size_t)b * D_;
  float ss = 0.f;
  for (int i = tid; i < D_; i += 256) { float v = x[i]; ss += v * v; }
  __shared__ float red[256];
  red[tid] = ss; __syncthreads();
  for (int s = 128; s; s >>= 1) { if (tid < s) red[tid] += red[tid + s]; __syncthreads(); }
  float r = rsqrtf(red[0] / (float)D_ + EPS_);
  float* o = out + (size_t)b * D_;
  for (int i = tid; i < D_; i += 256) o[i] = x[i] * r * w[i];
}

// ------------- row-split split-K GEMV: 4 waves/block, each wave owns <=NR rows -------------
template<int NR, int ROWS, int CHUNK, int UNROLL>
__device__ __forceinline__ void gemv_core(
    const float4* __restrict__ W4, const float (*xs)[ROWS],
    int i0, int N4, int j4, int r0, float* __restrict__ P, size_t pb, int N) {
  float4 acc[NR];
#pragma unroll
  for (int r = 0; r < NR; ++r) acc[r] = make_float4(0.f, 0.f, 0.f, 0.f);
  for (int iu = 0; iu < CHUNK; iu += UNROLL) {
    float4 w[UNROLL];
#pragma unroll
    for (int u = 0; u < UNROLL; ++u)
      w[u] = W4[(size_t)(i0 + iu + u) * N4 + j4];
#pragma unroll
    for (int u = 0; u < UNROLL; ++u) {
#pragma unroll
      for (int r = 0; r < NR; ++r) {
        float xv = xs[iu + u][r0 + r];
        acc[r].x += xv * w[u].x; acc[r].y += xv * w[u].y;
        acc[r].z += xv * w[u].z; acc[r].w += xv * w[u].w;
      }
    }
  }
#pragma unroll
  for (int r = 0; r < NR; ++r)
    *(float4*)&P[(pb + r) * (size_t)N + (size_t)4 * j4] = acc[r];
}

// grid = (N4/64, K/CHUNK, nmat); block = 256 (4 waves).
template<int ROWS, int RPG, int CHUNK, int UNROLL>
__global__ __launch_bounds__(256, 1) void gemv_rs(
    const float* __restrict__ X,
    const float* __restrict__ Wa, const float* __restrict__ Wb, const float* __restrict__ Wc,
    float* __restrict__ P, int N, int K) {
  const float* W = (blockIdx.z == 0) ? Wa : (blockIdx.z == 1) ? Wb : Wc;
  __shared__ float xs[CHUNK][ROWS];
  int tid = threadIdx.x;
  int i0 = blockIdx.y * CHUNK;
  for (int idx = tid; idx < ROWS * CHUNK; idx += 256) {
    int r = idx / CHUNK, ii = idx - r * CHUNK;
    xs[ii][r] = X[(size_t)r * K + i0 + ii];
  }
  __syncthreads();
  int wave = tid >> 6, lane = tid & 63;
  int r0 = wave * RPG;
  int N4 = N >> 2;
  int j4 = blockIdx.x * 64 + lane;
  const float4* W4 = (const float4*)W;
  size_t pb = ((size_t)blockIdx.z * gridDim.y + blockIdx.y) * ROWS + r0;
  constexpr int LAST = ROWS - 3 * RPG;
  if (r0 + RPG <= ROWS)
    gemv_core<RPG, ROWS, CHUNK, UNROLL>(W4, xs, i0, N4, j4, r0, P, pb, N);
  else if (LAST > 0)
    gemv_core<(LAST > 0 ? LAST : 1), ROWS, CHUNK, UNROLL>(W4, xs, i0, N4, j4, r0, P, pb, N);
}

// ------- QKV reduction over 16 chunks + fused RoPE on q,k rows 0..7 -------
// P: [z(3)][chunk(16)][row(18)][4096]
__global__ __launch_bounds__(256) void reduce3_rope_k(
    const float* __restrict__ P, const float* __restrict__ fc, const float* __restrict__ fs,
    float* __restrict__ Ya, float* __restrict__ Yb, float* __restrict__ Yc) {
  int z = blockIdx.z;
  int i4 = blockIdx.x * 256 + threadIdx.x;      // 18432 float4 per z
  const float4* P4 = (const float4*)P;
  size_t base = (size_t)z * 16 * 18432 + i4;
  float4 s = make_float4(0.f, 0.f, 0.f, 0.f);
#pragma unroll
  for (int c = 0; c < 16; ++c) {
    float4 v = P4[base + (size_t)c * 18432];
    s.x += v.x; s.y += v.y; s.z += v.z; s.w += v.w;
  }
  int row = i4 >> 10;
  if (z < 2 && row < 8) {
    int c0 = (i4 & 1023) << 2;
    int p0 = (c0 & 127) >> 1;
    float ca = fc[p0], sa = fs[p0], cb = fc[p0 + 1], sb = fs[p0 + 1];
    float4 r;
    r.x = s.x * ca - s.y * sa; r.y = s.x * sa + s.y * ca;
    r.z = s.z * cb - s.w * sb; r.w = s.z * sb + s.w * cb;
    s = r;
  }
  float4* Y = (float4*)(z == 0 ? Ya : z == 1 ? Yb : Yc);
  Y[i4] = s;
}

// ------- reduction with residual base: Y = base + sum_c P[c] ; 64 blocks x 128 thr -------
__global__ __launch_bounds__(128) void reduceB_k(const float* __restrict__ P,
                                                 const float* __restrict__ base,
                                                 float* __restrict__ Y, int n4, int nc) {
  int i4 = blockIdx.x * 128 + threadIdx.x;
  if (i4 >= n4) return;
  const float4* P4 = (const float4*)P;
  float4 s = ((const float4*)base)[i4];
  for (int c = 0; c < nc; ++c) {
    float4 v = P4[(size_t)c * n4 + i4];
    s.x += v.x; s.y += v.y; s.z += v.z; s.w += v.w;
  }
  ((float4*)Y)[i4] = s;
}

// ------- FFN: gb = silu(sum P[z=0]) * (sum P[z=1]) ; P [z(2)][chunk(8)][8][11008] -------
__global__ __launch_bounds__(128) void reduce_silu_k(const float* __restrict__ P,
                                                     float* __restrict__ gb) {
  int i4 = blockIdx.x * 128 + threadIdx.x;      // 172*128 = 22016 exact
  const float4* P4 = (const float4*)P;
  float4 a = make_float4(0.f, 0.f, 0.f, 0.f);
  float4 b = make_float4(0.f, 0.f, 0.f, 0.f);
#pragma unroll
  for (int c = 0; c < 8; ++c) {
    float4 u = P4[(size_t)c * 22016 + i4];
    float4 v = P4[(size_t)(8 + c) * 22016 + i4];
    a.x += u.x; a.y += u.y; a.z += u.z; a.w += u.w;
    b.x += v.x; b.y += v.y; b.z += v.z; b.w += v.w;
  }
  float4 o;
  o.x = (a.x / (1.f + __expf(-a.x))) * b.x;
  o.y = (a.y / (1.f + __expf(-a.y))) * b.y;
  o.z = (a.z / (1.f + __expf(-a.z))) * b.z;
  o.w = (a.w / (1.f + __expf(-a.w))) * b.w;
  ((float4*)gb)[i4] = o;
}

// ------------- attention pass 1: contiguous-streaming flash-decode -------------
// grid (NC_=128, B=8). Block handles ALL 32 heads for 16 consecutive positions:
// wave owns 8 heads (8 lanes/head, 16 floats/lane), so each position is one fully
// contiguous 16KB read and the block streams a contiguous 256KB region of ck/cv.
// Online softmax per 8-lane group; no __syncthreads.
// part[((b*NC_+c)*32+h)*132] = [m, l, pad, pad, o[128]]
__global__ __launch_bounds__(256, 4) void attn_partial(
    const float* __restrict__ qp,   // rows 0..7 = q, post-rope
    const float* __restrict__ ck,
    const float* __restrict__ cv,
    float* __restrict__ part) {
  int c = blockIdx.x, b = blockIdx.y;
  int tid = threadIdx.x, wave = tid >> 6, lane = tid & 63;
  int hl = lane >> 3;                  // head within wave's 8
  int h = wave * 8 + hl;
  int d0 = (lane & 7) << 4;            // 16 floats per lane
  const float4* q4 = (const float4*)&qp[(size_t)b * D_ + h * HD_ + d0];
  float4 q0 = q4[0], q1 = q4[1], q2 = q4[2], q3 = q4[3];
  int t0 = c * 16;
  size_t base = ((size_t)(b * MAXSEQ_ + t0)) * D_ + (size_t)h * HD_ + d0;
  float m = -INFINITY, l = 0.f;
  float4 o0 = make_float4(0.f,0.f,0.f,0.f), o1 = o0, o2 = o0, o3 = o0;
#pragma unroll 4
  for (int i = 0; i < 16; ++i) {
    size_t off = base + (size_t)i * D_;
    const float4* kp4 = (const float4*)&ck[off];
    float4 k0 = kp4[0], k1 = kp4[1], k2 = kp4[2], k3 = kp4[3];
    float s = q0.x*k0.x + q0.y*k0.y + q0.z*k0.z + q0.w*k0.w
            + q1.x*k1.x + q1.y*k1.y + q1.z*k1.z + q1.w*k1.w
            + q2.x*k2.x + q2.y*k2.y + q2.z*k2.z + q2.w*k2.w
            + q3.x*k3.x + q3.y*k3.y + q3.z*k3.z + q3.w*k3.w;
    s += __shfl_xor(s, 1); s += __shfl_xor(s, 2); s += __shfl_xor(s, 4);
    s *= SCALE_;
    if (t0 + i == MAXSEQ_ - 1) s = -1e30f;   // new token folded in combine
    float mn = fmaxf(m, s);
    float r = __expf(m - mn), p = __expf(s - mn);
    const float4* vp4 = (const float4*)&cv[off];
    float4 v0 = vp4[0], v1 = vp4[1], v2 = vp4[2], v3 = vp4[3];
    o0.x = o0.x*r + p*v0.x; o0.y = o0.y*r + p*v0.y; o0.z = o0.z*r + p*v0.z; o0.w = o0.w*r + p*v0.w;
    o1.x = o1.x*r + p*v1.x; o1.y = o1.y*r + p*v1.y; o1.z = o1.z*r + p*v1.z; o1.w = o1.w*r + p*v1.w;
    o2.x = o2.x*r + p*v2.x; o2.y = o2.y*r + p*v2.y; o2.z = o2.z*r + p*v2.z; o2.w = o2.w*r + p*v2.w;
    o3.x = o3.x*r + p*v3.x; o3.y = o3.y*r + p*v3.y; o3.z = o3.z*r + p*v3.z; o3.w = o3.w*r + p*v3.w;
    l = l * r + p; m = mn;
  }
  float* po = &part[(((size_t)b * NC_ + c) * H_ + h) * 132];
  if ((lane & 7) == 0) { po[0] = m; po[1] = l; }
  float4* po4 = (float4*)&po[4 + d0];
  po4[0] = o0; po4[1] = o1; po4[2] = o2; po4[3] = o3;
}

// --- attention pass 2: combine 128 partials + new token + adapter (shuffle-based) ---
__global__ __launch_bounds__(128) void attn_combine(
    const float* __restrict__ part,
    const float* __restrict__ qp,
    const float* __restrict__ kvk,  // rows 0..7 = new k (roped), rows 8..17 = ak
    const float* __restrict__ kvv,  // rows 0..7 = new v,         rows 8..17 = av
    const float* __restrict__ gate,
    float* __restrict__ attn) {
  int bh = blockIdx.x;
  int h = bh & 31, b = bh >> 5;
  int tid = threadIdx.x;            // = d in [0,128)
  int wave = tid >> 6, lane = tid & 63;
  const size_t cs = (size_t)H_ * 132;               // stride between chunks
  const float* pb = &part[((size_t)b * NC_ * H_ + h) * 132];
  __shared__ float sm[NC_], sl[NC_], red[NC_];
  sm[tid] = pb[cs * tid];
  sl[tid] = pb[cs * tid + 1];
  __syncthreads();
  red[tid] = sm[tid]; __syncthreads();
  for (int s = 64; s; s >>= 1) { if (tid < s) red[tid] = fmaxf(red[tid], red[tid + s]); __syncthreads(); }
  float M = red[0];
  float L = 0.f, O = 0.f;
#pragma unroll 4
  for (int c2 = 0; c2 < NC_; ++c2) {
    float e = __expf(sm[c2] - M);
    L += e * sl[c2];
    O += e * pb[cs * c2 + 4 + tid];
  }
  // ---- shuffle-based scores: new token (idx 10) + 10 adapter keys ----
  size_t qi = (size_t)b * D_ + h * HD_ + tid;
  float qd = qp[qi];
  __shared__ float s2[2][12];
  {
    float pr = qd * kvk[qi];
    pr += __shfl_xor(pr, 32); pr += __shfl_xor(pr, 16); pr += __shfl_xor(pr, 8);
    pr += __shfl_xor(pr, 4);  pr += __shfl_xor(pr, 2);  pr += __shfl_xor(pr, 1);
    if (lane == 0) s2[wave][10] = pr;
  }
  for (int j = 0; j < 10; ++j) {
    float pr = qd * kvk[(size_t)(8 + j) * D_ + h * HD_ + tid];
    pr += __shfl_xor(pr, 32); pr += __shfl_xor(pr, 16); pr += __shfl_xor(pr, 8);
    pr += __shfl_xor(pr, 4);  pr += __shfl_xor(pr, 2);  pr += __shfl_xor(pr, 1);
    if (lane == 0) s2[wave][j] = pr;
  }
  __syncthreads();
  float s_new = (s2[0][10] + s2[1][10]) * SCALE_;
  float M2 = fmaxf(M, s_new);
  float eM = __expf(M - M2), eN = __expf(s_new - M2);
  L = L * eM + eN;
  O = O * eM + eN * kvv[qi];
  float main_out = O / L;
  float ma = -INFINITY, sa[10];
  for (int j = 0; j < 10; ++j) { sa[j] = (s2[0][j] + s2[1][j]) * SCALE_; ma = fmaxf(ma, sa[j]); }
  float la = 0.f, pj[10];
  for (int j = 0; j < 10; ++j) { pj[j] = __expf(sa[j] - ma); la += pj[j]; }
  float ao = 0.f;
  for (int j = 0; j < 10; ++j) ao += pj[j] * kvv[(size_t)(8 + j) * D_ + h * HD_ + tid];
  ao /= la;
  float g = tanhf(gate[h]);
  attn[qi] = main_out + g * ao;
}

extern "C" void kernel_launch(void* const* d_in, const int* in_sizes, int n_in,
                              void* d_out, int out_size, void* d_ws, size_t ws_size,
                              hipStream_t stream) {
  (void)in_sizes; (void)n_in; (void)out_size; (void)ws_size;
  const float* x       = (const float*)d_in[0];
  const float* adapter = (const float*)d_in[1];
  const float* ck      = (const float*)d_in[2];
  const float* cv      = (const float*)d_in[3];
  const float* fc      = (const float*)d_in[4];
  const float* fs      = (const float*)d_in[5];
  const float* wq      = (const float*)d_in[6];
  const float* wk      = (const float*)d_in[7];
  const float* wv      = (const float*)d_in[8];
  const float* wo      = (const float*)d_in[9];
  const float* gate    = (const float*)d_in[10];
  const float* anw     = (const float*)d_in[11];
  const float* fnw     = (const float*)d_in[12];
  const float* w1      = (const float*)d_in[13];
  const float* w2      = (const float*)d_in[14];
  const float* w3      = (const float*)d_in[15];
  float* out = (float*)d_out;

  float* ws      = (float*)d_ws;
  float* xa      = ws;                     // 18*4096
  float* qp      = xa + 18 * D_;           // 18*4096 (rows 0..7 valid)
  float* kp      = qp + 18 * D_;           // rows 0..7 = new k (roped), 8..17 = ak
  float* vp      = kp + 18 * D_;           // rows 0..7 = new v, 8..17 = av
  float* attn    = vp + 18 * D_;           // 8*4096
  float* hbuf    = attn + 8 * D_;          // 8*4096
  float* hn      = hbuf + 8 * D_;          // 8*4096
  float* gb      = hn + 8 * D_;            // 8*11008
  float* scratch = gb + 8 * FF_;           // max phase: attn part 8*128*32*132 = 4,325,376 floats
  // scratch phases (time-disjoint): Pqkv 13.5MB | part 17.3MB | Pwo 4.2MB | Pffn 5.6MB | Pw2 4.2MB

  // 1) xa = [rmsnorm(x); adapter]
  norm_adapter_k<<<18, 256, 0, stream>>>(x, anw, adapter, xa);
  // 2) QKV (+adapter K/V) projections -> partials -> reduce (+rope q,k rows 0..7)
  gemv_rs<18, 5, 256, 16><<<dim3(16, 16, 3), 256, 0, stream>>>(xa, wq, wk, wv, scratch, D_, D_);
  reduce3_rope_k<<<dim3(72, 1, 3), 256, 0, stream>>>(scratch, fc, fs, qp, kp, vp);
  // 3) contiguous-streaming flash-decode (new token folded in combine)
  attn_partial<<<dim3(NC_, 8), 256, 0, stream>>>(qp, ck, cv, scratch);
  attn_combine<<<256, 128, 0, stream>>>(scratch, qp, kp, vp, gate, attn);
  // 4) h = x + attn @ wo
  gemv_rs<8, 2, 128, 16><<<dim3(16, 32, 1), 256, 0, stream>>>(attn, wo, wo, wo, scratch, D_, D_);
  reduceB_k<<<64, 128, 0, stream>>>(scratch, x, hbuf, 8192, 32);
  // 5) hn = rmsnorm(h); FFN up+gate -> fused reduce+silu
  rmsnorm_k<<<8, 256, 0, stream>>>(hbuf, fnw, hn);
  gemv_rs<8, 2, 512, 16><<<dim3(43, 8, 2), 256, 0, stream>>>(hn, w1, w3, w3, scratch, FF_, D_);
  reduce_silu_k<<<172, 128, 0, stream>>>(scratch, gb);
  // 6) out = h + gb @ w2
  gemv_rs<8, 2, 344, 8><<<dim3(16, 32, 1), 256, 0, stream>>>(gb, w2, w2, w2, scratch, D_, FF_);
  reduceB_k<<<64, 128, 0, stream>>>(scratch, hbuf, out, 8192, 32);
}